// Round 8
// baseline (415.211 us; speedup 1.0000x reference)
//
#include <hip/hip_runtime.h>
#include <hip/hip_bf16.h>
#include <stdint.h>

#define D 128
#define BCAP 18432              // bucket capacity: mean 16384, +16 sigma
#define CPAD 32                 // bcur cursor padding: 1 cursor per 128B line
#define HCAP 9216               // half-bucket LDS stage cap: mean 8192, +11 sigma
typedef unsigned short u16;
typedef unsigned int u32;
typedef __attribute__((ext_vector_type(8))) short bf16x8;
typedef __attribute__((ext_vector_type(4))) float f32x4;
typedef __attribute__((ext_vector_type(2))) float f32x2;
typedef __attribute__((ext_vector_type(2))) unsigned int u32x2;

// ---------- helpers ----------
__device__ inline u16 f_to_bf16(float f) {             // round-to-nearest-even
    u32 u = __builtin_bit_cast(u32, f);
    u += 0x7FFFu + ((u >> 16) & 1u);
    return (u16)(u >> 16);
}
__device__ inline u32 pack_bf16(float a, float b) {
    return (u32)f_to_bf16(a) | ((u32)f_to_bf16(b) << 16);
}

// ---------- kernel 0: zero counters ----------
__global__ void zero_ints(int* __restrict__ p, int n) {
    int i = blockIdx.x * blockDim.x + threadIdx.x;
    if (i < n) p[i] = 0;
}

// ---------- fused prep: bin_edges (blocks [0,binB)) + convert_x + convert_w ----------
__global__ __launch_bounds__(256) void prep_fused(
    const int* __restrict__ src, const int* __restrict__ dst, int E, int nbuck, int binB,
    u32* __restrict__ pairs, int* __restrict__ bcur,
    const float* __restrict__ x, u16* __restrict__ xb, int nf4, int convB,
    const float* __restrict__ Wl1, const float* __restrict__ Wr1,
    const float* __restrict__ Wl2, const float* __restrict__ Wr2,
    u16* __restrict__ WT1, u16* __restrict__ WT2) {
    __shared__ int hist[128], gb[128], loc[128];
    int tid = threadIdx.x;
    int bid = blockIdx.x;
    if (bid < binB) {
        // ---- bin edges into 1024-node buckets ----
        if (tid < 128) { hist[tid] = 0; loc[tid] = 0; }
        __syncthreads();
        int base = bid * 4096;
        int d[16], b[16];
        #pragma unroll
        for (int i = 0; i < 16; ++i) {
            int e = base + i * 256 + tid;
            d[i] = (e < E) ? dst[e] : -1;
            b[i] = (d[i] >= 0) ? (d[i] >> 10) : -1;
            if (b[i] >= 0) atomicAdd(&hist[b[i]], 1);
        }
        __syncthreads();
        if (tid < nbuck && hist[tid] > 0) gb[tid] = atomicAdd(&bcur[tid * CPAD], hist[tid]);
        __syncthreads();
        #pragma unroll
        for (int i = 0; i < 16; ++i) {
            if (b[i] >= 0) {
                int e = base + i * 256 + tid;
                int s = src[e];
                int r = atomicAdd(&loc[b[i]], 1);
                int pos = gb[b[i]] + r;
                if (pos < BCAP)     // overflow impossible for uniform-random edges
                    pairs[(size_t)b[i] * BCAP + pos] = ((u32)s << 10) | ((u32)d[i] & 1023u);
            }
        }
    } else if (bid < binB + convB) {
        // ---- convert x fp32 -> bf16, float4-vectorized grid-stride ----
        int idx = (bid - binB) * 256 + tid;
        int stride = convB * 256;
        const float4* xf = (const float4*)x;
        uint2* xo = (uint2*)xb;
        for (int i = idx; i < nf4; i += stride) {
            float4 v = xf[i];
            xo[i] = make_uint2(pack_bf16(v.x, v.y), pack_bf16(v.z, v.w));
        }
    } else {
        // ---- convert weights -> WT[n][k] bf16, k = [Wl cols | Wr cols] ----
        int id = (bid - binB - convB) * 256 + tid;   // 256 blocks x 256 = 65536
        if (id < 2 * 128 * 256) {
            int which = id >> 15;
            int rem = id & 32767;
            int n = rem >> 8;
            int k = rem & 255;
            const float* Wl = which ? Wl2 : Wl1;
            const float* Wr = which ? Wr2 : Wr1;
            float v = (k < 128) ? Wl[k * 128 + n] : Wr[(k - 128) * 128 + n];
            u16* WT = which ? WT2 : WT1;
            WT[n * 256 + k] = f_to_bf16(v);
        }
    }
}

// ---------- phase 2: per-bucket CSR build; LDS-staged scatter, coalesced writeback ----------
__global__ __launch_bounds__(1024) void build_csr(
    const u32* __restrict__ pairs, const int* __restrict__ bcur, int N,
    int* __restrict__ cnt, int* __restrict__ seg_start, int* __restrict__ gtotal,
    int* __restrict__ csr_src) {
    __shared__ int cnt_l[1024];
    __shared__ int off_l[1024];
    __shared__ int sblk[1024];
    __shared__ u32 stage[HCAP];
    __shared__ int gbase_s;
    int tid = threadIdx.x;
    int bk = blockIdx.x;
    int n0 = bk << 10;
    int nN = min(1024, N - n0);
    cnt_l[tid] = 0;
    __syncthreads();
    int m = min(bcur[bk * CPAD], BCAP);
    const u32* P = pairs + (size_t)bk * BCAP;
    for (int i = tid; i < m; i += 1024) {
        atomicAdd(&cnt_l[P[i] & 1023u], 1);
    }
    __syncthreads();
    int c = cnt_l[tid];
    sblk[tid] = c;
    for (int off = 1; off < 1024; off <<= 1) {   // uniform loop: barrier-safe
        __syncthreads();
        int u = (tid >= off) ? sblk[tid - off] : 0;
        __syncthreads();
        sblk[tid] += u;
    }
    int excl = sblk[tid] - c;                    // own slot only: no race
    off_l[tid] = excl;
    if (tid == 1023) gbase_s = atomicAdd(gtotal, sblk[1023]);
    __syncthreads();
    int gbase = gbase_s;
    if (tid < nN) {
        cnt[n0 + tid] = c;
        seg_start[n0 + tid] = gbase + excl;
    }
    int total = sblk[1023];
    int hstart1 = off_l[512];                    // edges with dst_local < 512
    __syncthreads();
    #pragma unroll
    for (int half = 0; half < 2; ++half) {
        int hstart = half ? hstart1 : 0;
        int hcount = half ? (total - hstart1) : hstart1;
        if (hcount > HCAP) hcount = HCAP;        // statistically impossible
        if (tid < 512) cnt_l[tid] = 0;           // reuse as cursors
        __syncthreads();
        for (int i = tid; i < m; i += 1024) {
            u32 e = P[i];
            int dl = (int)(e & 1023u);
            if ((dl >> 9) == half) {
                int r = atomicAdd(&cnt_l[dl & 511], 1);
                int idx = off_l[dl] - hstart + r;
                if (idx < HCAP) stage[idx] = e >> 10;
            }
        }
        __syncthreads();
        for (int j = tid; j < hcount; j += 1024)
            csr_src[gbase + hstart + j] = (int)stage[j];   // coalesced
        __syncthreads();
    }
}

// ---------- fused layer: 16 waves aggregate 16 nodes (1 wave/node, r2 TLP
// preserved) -> 4KB LDS tile -> waves 0-7 do the 16-row MFMA GEMM ----------
// r6's failure was 16 nodes SERIAL per wave (TLP collapse); here the gather
// phase is instruction-identical to the r2 aggregate (1 wave per node,
// 100K waves). Saves per layer: aggb HBM round-trip (51MB), the gemm
// dispatch's A-streaming, and one launch boundary.
// GEMM B (WT) read direct from L2 (64KB/block; no K-loop reuse problem at
// 8 MFMAs since acc is a single f32x4 and all 8 b-frags prefetchable).
// LDS tile XOR-swizzled (chunk^row) -> A-frag ds_read conflict-free.
template<int OUT_BF16>
__global__ __launch_bounds__(1024, 8) void sage_layer(
    const u16* __restrict__ feat, const int* __restrict__ csr_src,
    const int* __restrict__ seg_start, const int* __restrict__ cnt,
    const u16* __restrict__ WT, const float* __restrict__ bias,
    void* __restrict__ out, int N) {
    __shared__ __align__(16) u16 tile[16 * 128];    // 16 rows x 128 dims = 4KB
    int wv = threadIdx.x >> 6;          // 0..15: one node per wave
    int lane = threadIdx.x & 63;
    int sub = lane & 15;                // 16B chunk within row
    int eoff = lane >> 4;               // 4 edges in flight
    int nb = blockIdx.x * 16;
    int n = nb + wv;

    // ---- phase 1: aggregate node n (r2 inner loop, unchanged) ----
    if (n < N) {
        int s0 = seg_start[n];
        int deg = cnt[n];
        f32x2 acc2[4];
        #pragma unroll
        for (int i = 0; i < 4; ++i) acc2[i] = (f32x2){0.f, 0.f};
        for (int c0 = 0; c0 < deg; c0 += 64) {
            int chunkN = min(deg - c0, 64);
            int myidx = (lane < chunkN) ? csr_src[s0 + c0 + lane] : 0;  // coalesced
            for (int e0 = 0; e0 < chunkN; e0 += 16) {
                uint4 v[4];
                #pragma unroll
                for (int j = 0; j < 4; ++j) {
                    int ej = e0 + j * 4 + eoff;
                    if (e0 + j * 4 < chunkN) {          // wave-uniform: cheap skip
                        int s = __shfl(myidx, ej & 63);
                        if (ej < chunkN)                // per-lane: no dup loads
                            v[j] = ((const uint4*)(feat + (size_t)s * 128))[sub];
                    }
                }
                #pragma unroll
                for (int j = 0; j < 4; ++j) {
                    int ej = e0 + j * 4 + eoff;
                    if (ej < chunkN) {
                        u32 w;
                        w = v[j].x; acc2[0] += __builtin_bit_cast(f32x2, (u32x2){w << 16, w & 0xFFFF0000u});
                        w = v[j].y; acc2[1] += __builtin_bit_cast(f32x2, (u32x2){w << 16, w & 0xFFFF0000u});
                        w = v[j].z; acc2[2] += __builtin_bit_cast(f32x2, (u32x2){w << 16, w & 0xFFFF0000u});
                        w = v[j].w; acc2[3] += __builtin_bit_cast(f32x2, (u32x2){w << 16, w & 0xFFFF0000u});
                    }
                }
            }
        }
        float a[8];
        #pragma unroll
        for (int i = 0; i < 4; ++i) { a[2 * i] = acc2[i].x; a[2 * i + 1] = acc2[i].y; }
        #pragma unroll
        for (int i = 0; i < 8; ++i) {
            a[i] += __shfl_xor(a[i], 16);
            a[i] += __shfl_xor(a[i], 32);
        }
        if (eoff == 0) {
            float inv = 1.0f / fmaxf((float)deg, 1.0f);
            uint4 o;
            o.x = pack_bf16(a[0] * inv, a[1] * inv);
            o.y = pack_bf16(a[2] * inv, a[3] * inv);
            o.z = pack_bf16(a[4] * inv, a[5] * inv);
            o.w = pack_bf16(a[6] * inv, a[7] * inv);
            *(uint4*)&tile[wv * 128 + ((sub ^ wv) * 8)] = o;   // swizzled row park
        }
    }
    __syncthreads();

    // ---- phase 2: GEMM out[16 rows] = relu([agg|x] @ WT^T + bias) ----
    // wave t (= wv, 0..7) computes col-tile cols 16t..16t+15; waves 8-15 idle.
    if (wv < 8) {
        int t = wv;
        int col = sub;
        int chunk = eoff;
        size_t m0 = (size_t)nb + col;
        size_t m0c = (m0 < (size_t)N) ? m0 : (size_t)(N - 1);
        const bf16x8* x0p = (const bf16x8*)(feat + m0c * 128 + chunk * 8);

        f32x4 acc = (f32x4){0.f, 0.f, 0.f, 0.f};
        // agg half: kc = 4s + chunk, A from swizzled LDS (phys = kc ^ row)
        #pragma unroll
        for (int s = 0; s < 4; ++s) {
            int kc = s * 4 + chunk;
            bf16x8 a0 = *(const bf16x8*)&tile[col * 128 + ((kc ^ col) * 8)];
            bf16x8 b = *(const bf16x8*)(WT + (size_t)(16 * t + col) * 256 + kc * 8);
            acc = __builtin_amdgcn_mfma_f32_16x16x32_bf16(a0, b, acc, 0, 0, 0);
        }
        // x half: kc = 16 + 4s + chunk, A from global feat rows
        #pragma unroll
        for (int s = 0; s < 4; ++s) {
            bf16x8 a0 = x0p[s * 4];
            int kc = 16 + s * 4 + chunk;
            bf16x8 b = *(const bf16x8*)(WT + (size_t)(16 * t + col) * 256 + kc * 8);
            acc = __builtin_amdgcn_mfma_f32_16x16x32_bf16(a0, b, acc, 0, 0, 0);
        }

        // epilogue: C/D layout col=lane&15, row=(lane>>4)*4+reg  [m89-verified]
        size_t row0 = (size_t)nb + chunk * 4;
        int nc = 16 * t + col;
        float bv = bias[nc];
        #pragma unroll
        for (int r = 0; r < 4; ++r) {
            size_t row = row0 + r;
            if (row < (size_t)N) {
                float v = fmaxf(acc[r] + bv, 0.f);
                if (OUT_BF16) ((u16*)out)[row * 128 + nc] = f_to_bf16(v);
                else          ((float*)out)[row * 128 + nc] = v;
            }
        }
    }
}

extern "C" void kernel_launch(void* const* d_in, const int* in_sizes, int n_in,
                              void* d_out, int out_size, void* d_ws, size_t ws_size,
                              hipStream_t stream) {
    const float* x   = (const float*)d_in[0];
    const int*   ei  = (const int*)d_in[1];   // int64 -> int32 from harness
    const float* Wl1 = (const float*)d_in[2];
    const float* Wr1 = (const float*)d_in[3];
    const float* b1  = (const float*)d_in[4];
    const float* Wl2 = (const float*)d_in[5];
    const float* Wr2 = (const float*)d_in[6];
    const float* b2  = (const float*)d_in[7];
    float* out       = (float*)d_out;

    int N = in_sizes[0] / D;        // 100000
    int E = in_sizes[1] / 2;        // 1600000
    const int* src = ei;
    const int* dst = ei + E;
    int nbuck = (N + 1023) >> 10;   // 98

    // workspace carve-up
    char* ws = (char*)d_ws;
    int* cnt       = (int*)ws;  ws += (size_t)N * 4;       // degrees
    int* seg_start = (int*)ws;  ws += (size_t)N * 4;       // segment bases
    int* bcur      = (int*)ws;  ws += 128 * CPAD * 4;      // padded bucket cursors
    int* gtotal    = (int*)ws;  ws += 4 * 4;               // global segment cursor
    ws = (char*)(((uintptr_t)ws + 255) & ~(uintptr_t)255);
    int* csr_src   = (int*)ws;  ws += (size_t)E * 4;
    ws = (char*)(((uintptr_t)ws + 255) & ~(uintptr_t)255);
    u16* WT1       = (u16*)ws;  ws += (size_t)128 * 256 * 2;
    u16* WT2       = (u16*)ws;  ws += (size_t)128 * 256 * 2;
    ws = (char*)(((uintptr_t)ws + 255) & ~(uintptr_t)255);
    u32* pairs     = (u32*)ws;  ws += (size_t)128 * BCAP * 4;   // 9.4 MB bin scratch
    ws = (char*)(((uintptr_t)ws + 255) & ~(uintptr_t)255);
    u16* h1b       = (u16*)ws;  ws += (size_t)N * 128 * 2;
    u16* xb        = (u16*)d_out;       // parks in d_out; dead before layer2 writes out

    // zero padded bcur (128*CPAD) + gtotal (contiguous)
    zero_ints<<<(128 * CPAD + 4 + 255) / 256, 256, 0, stream>>>(bcur, 128 * CPAD + 4);

    int binB  = (E + 4095) / 4096;      // 391
    int convB = 2048;                   // grid-stride float4 conversion
    int nf4   = N * (D / 4);            // 3.2M float4s
    prep_fused<<<binB + convB + 256, 256, 0, stream>>>(
        src, dst, E, nbuck, binB, pairs, bcur,
        x, xb, nf4, convB, Wl1, Wr1, Wl2, Wr2, WT1, WT2);

    build_csr<<<nbuck, 1024, 0, stream>>>(pairs, bcur, N, cnt, seg_start, gtotal, csr_src);

    int layerBlocks = (N + 15) / 16;    // 6250: 16 waves/block, 1 node/wave

    // layer 1: xb -> h1b (bf16)
    sage_layer<1><<<layerBlocks, 1024, 0, stream>>>(xb, csr_src, seg_start, cnt, WT1, b1, h1b, N);
    // layer 2: h1b -> out (f32)
    sage_layer<0><<<layerBlocks, 1024, 0, stream>>>(h1b, csr_src, seg_start, cnt, WT2, b2, out, N);
}

// Round 9
// 305.656 us; speedup vs baseline: 1.3584x; 1.3584x over previous
//
#include <hip/hip_runtime.h>
#include <hip/hip_bf16.h>
#include <stdint.h>

#define D 128
#define BCAP 18432              // bucket capacity: mean 16384, +16 sigma
#define CPAD 32                 // bcur cursor padding: 1 cursor per 128B line
#define HCAP 9216               // half-bucket LDS stage cap: mean 8192, +11 sigma
typedef unsigned short u16;
typedef unsigned int u32;
typedef __attribute__((ext_vector_type(8))) short bf16x8;
typedef __attribute__((ext_vector_type(4))) float f32x4;
typedef __attribute__((ext_vector_type(2))) float f32x2;
typedef __attribute__((ext_vector_type(2))) unsigned int u32x2;

// ---------- helpers ----------
__device__ inline u16 f_to_bf16(float f) {             // round-to-nearest-even
    u32 u = __builtin_bit_cast(u32, f);
    u += 0x7FFFu + ((u >> 16) & 1u);
    return (u16)(u >> 16);
}
__device__ inline u32 pack_bf16(float a, float b) {
    return (u32)f_to_bf16(a) | ((u32)f_to_bf16(b) << 16);
}

// ---------- fused prep: bin_edges (blocks [0,binB)) + convert_x + convert_w ----------
__global__ __launch_bounds__(256) void prep_fused(
    const int* __restrict__ src, const int* __restrict__ dst, int E, int nbuck, int binB,
    u32* __restrict__ pairs, int* __restrict__ bcur,
    const float* __restrict__ x, u16* __restrict__ xb, int nf4, int convB,
    const float* __restrict__ Wl1, const float* __restrict__ Wr1,
    const float* __restrict__ Wl2, const float* __restrict__ Wr2,
    u16* __restrict__ WT1, u16* __restrict__ WT2) {
    __shared__ int hist[128], gb[128], loc[128];
    int tid = threadIdx.x;
    int bid = blockIdx.x;
    if (bid < binB) {
        // ---- bin edges into 1024-node buckets ----
        if (tid < 128) { hist[tid] = 0; loc[tid] = 0; }
        __syncthreads();
        int base = bid * 4096;
        int d[16], b[16];
        #pragma unroll
        for (int i = 0; i < 16; ++i) {
            int e = base + i * 256 + tid;
            d[i] = (e < E) ? dst[e] : -1;
            b[i] = (d[i] >= 0) ? (d[i] >> 10) : -1;
            if (b[i] >= 0) atomicAdd(&hist[b[i]], 1);
        }
        __syncthreads();
        if (tid < nbuck && hist[tid] > 0) gb[tid] = atomicAdd(&bcur[tid * CPAD], hist[tid]);
        __syncthreads();
        #pragma unroll
        for (int i = 0; i < 16; ++i) {
            if (b[i] >= 0) {
                int e = base + i * 256 + tid;
                int s = src[e];
                int r = atomicAdd(&loc[b[i]], 1);
                int pos = gb[b[i]] + r;
                if (pos < BCAP)     // overflow impossible for uniform-random edges
                    pairs[(size_t)b[i] * BCAP + pos] = ((u32)s << 10) | ((u32)d[i] & 1023u);
            }
        }
    } else if (bid < binB + convB) {
        // ---- convert x fp32 -> bf16, float4-vectorized grid-stride ----
        int idx = (bid - binB) * 256 + tid;
        int stride = convB * 256;
        const float4* xf = (const float4*)x;
        uint2* xo = (uint2*)xb;
        for (int i = idx; i < nf4; i += stride) {
            float4 v = xf[i];
            xo[i] = make_uint2(pack_bf16(v.x, v.y), pack_bf16(v.z, v.w));
        }
    } else {
        // ---- convert weights -> WT[n][k] bf16, k = [Wl cols | Wr cols] ----
        int id = (bid - binB - convB) * 256 + tid;   // 256 blocks x 256 = 65536
        if (id < 2 * 128 * 256) {
            int which = id >> 15;
            int rem = id & 32767;
            int n = rem >> 8;
            int k = rem & 255;
            const float* Wl = which ? Wl2 : Wl1;
            const float* Wr = which ? Wr2 : Wr1;
            float v = (k < 128) ? Wl[k * 128 + n] : Wr[(k - 128) * 128 + n];
            u16* WT = which ? WT2 : WT1;
            WT[n * 256 + k] = f_to_bf16(v);
        }
    }
}

// ---------- phase 2: per-bucket CSR build; LDS-staged scatter, coalesced writeback ----------
__global__ __launch_bounds__(1024) void build_csr(
    const u32* __restrict__ pairs, const int* __restrict__ bcur, int N,
    int* __restrict__ cnt, int* __restrict__ seg_start, int* __restrict__ gtotal,
    int* __restrict__ csr_src) {
    __shared__ int cnt_l[1024];
    __shared__ int off_l[1024];
    __shared__ int sblk[1024];
    __shared__ u32 stage[HCAP];
    __shared__ int gbase_s;
    int tid = threadIdx.x;
    int bk = blockIdx.x;
    int n0 = bk << 10;
    int nN = min(1024, N - n0);
    cnt_l[tid] = 0;
    __syncthreads();
    int m = min(bcur[bk * CPAD], BCAP);
    const u32* P = pairs + (size_t)bk * BCAP;
    for (int i = tid; i < m; i += 1024) {
        atomicAdd(&cnt_l[P[i] & 1023u], 1);
    }
    __syncthreads();
    int c = cnt_l[tid];
    sblk[tid] = c;
    for (int off = 1; off < 1024; off <<= 1) {   // uniform loop: barrier-safe
        __syncthreads();
        int u = (tid >= off) ? sblk[tid - off] : 0;
        __syncthreads();
        sblk[tid] += u;
    }
    int excl = sblk[tid] - c;                    // own slot only: no race
    off_l[tid] = excl;
    if (tid == 1023) gbase_s = atomicAdd(gtotal, sblk[1023]);
    __syncthreads();
    int gbase = gbase_s;
    if (tid < nN) {
        cnt[n0 + tid] = c;
        seg_start[n0 + tid] = gbase + excl;
    }
    int total = sblk[1023];
    int hstart1 = off_l[512];                    // edges with dst_local < 512
    __syncthreads();
    #pragma unroll
    for (int half = 0; half < 2; ++half) {
        int hstart = half ? hstart1 : 0;
        int hcount = half ? (total - hstart1) : hstart1;
        if (hcount > HCAP) hcount = HCAP;        // statistically impossible
        if (tid < 512) cnt_l[tid] = 0;           // reuse as cursors
        __syncthreads();
        for (int i = tid; i < m; i += 1024) {
            u32 e = P[i];
            int dl = (int)(e & 1023u);
            if ((dl >> 9) == half) {
                int r = atomicAdd(&cnt_l[dl & 511], 1);
                int idx = off_l[dl] - hstart + r;
                if (idx < HCAP) stage[idx] = e >> 10;
            }
        }
        __syncthreads();
        for (int j = tid; j < hcount; j += 1024)
            csr_src[gbase + hstart + j] = (int)stage[j];   // coalesced
        __syncthreads();
    }
}

// ---------- mean-aggregate: one wave/node, 16 lanes/row x 16B (round-2 form) ----------
// PINNED at its structural floor: per-XCD L2 cold-fill of the 25.6MB table
// (~179MB L2-miss traffic at ~3.3TB/s -> ~62us). Fusion attempts both lost:
// r6 (16 nodes serial/wave, TLP collapse) and r8 (barrier straggler, 1.6x).
__global__ __launch_bounds__(256) void aggregate_bf16(
    const u16* __restrict__ xb, const int* __restrict__ csr_src,
    const int* __restrict__ seg_start, const int* __restrict__ cnt,
    int N, u16* __restrict__ agg) {
    int wave = threadIdx.x >> 6;
    int lane = threadIdx.x & 63;
    int n = blockIdx.x * (blockDim.x >> 6) + wave;
    if (n >= N) return;
    int s0 = seg_start[n];
    int deg = cnt[n];
    int sub = lane & 15;
    int eoff = lane >> 4;

    f32x2 acc2[4];
    #pragma unroll
    for (int i = 0; i < 4; ++i) acc2[i] = (f32x2){0.f, 0.f};

    for (int c0 = 0; c0 < deg; c0 += 64) {
        int chunkN = min(deg - c0, 64);
        int myidx = (lane < chunkN) ? csr_src[s0 + c0 + lane] : 0;  // coalesced
        for (int e0 = 0; e0 < chunkN; e0 += 16) {
            uint4 v[4];
            #pragma unroll
            for (int j = 0; j < 4; ++j) {
                int ej = e0 + j * 4 + eoff;
                if (e0 + j * 4 < chunkN) {          // wave-uniform: cheap skip
                    int s = __shfl(myidx, ej & 63);
                    if (ej < chunkN)                // per-lane: no dup loads
                        v[j] = ((const uint4*)(xb + (size_t)s * 128))[sub];
                }
            }
            #pragma unroll
            for (int j = 0; j < 4; ++j) {
                int ej = e0 + j * 4 + eoff;
                if (ej < chunkN) {
                    u32 w;
                    w = v[j].x; acc2[0] += __builtin_bit_cast(f32x2, (u32x2){w << 16, w & 0xFFFF0000u});
                    w = v[j].y; acc2[1] += __builtin_bit_cast(f32x2, (u32x2){w << 16, w & 0xFFFF0000u});
                    w = v[j].z; acc2[2] += __builtin_bit_cast(f32x2, (u32x2){w << 16, w & 0xFFFF0000u});
                    w = v[j].w; acc2[3] += __builtin_bit_cast(f32x2, (u32x2){w << 16, w & 0xFFFF0000u});
                }
            }
        }
    }

    float a[8];
    #pragma unroll
    for (int i = 0; i < 4; ++i) { a[2 * i] = acc2[i].x; a[2 * i + 1] = acc2[i].y; }
    #pragma unroll
    for (int i = 0; i < 8; ++i) {
        a[i] += __shfl_xor(a[i], 16);
        a[i] += __shfl_xor(a[i], 32);
    }

    if (eoff == 0) {
        float inv = 1.0f / fmaxf((float)deg, 1.0f);
        uint4 o;
        o.x = pack_bf16(a[0] * inv, a[1] * inv);
        o.y = pack_bf16(a[2] * inv, a[3] * inv);
        o.z = pack_bf16(a[4] * inv, a[5] * inv);
        o.w = pack_bf16(a[6] * inv, a[7] * inv);
        ((uint4*)(agg + (size_t)n * 128))[sub] = o;
    }
}

// ---------- fused GEMM: out = relu([Aa|Ax] @ WT^T + bias) via MFMA ----------
// 512-thread blocks: 8 waves share ONE 64KB B-stage (LDS/CU unchanged at 2
// blocks x 64KB = 128 <= 160KB) -> 16 waves/CU = 4/SIMD, double the latency
// hiding for the HBM A-streams vs the 256-thread form (2/SIMD, est ~55us).
// B staged with 16B-chunk XOR swizzle; direct-scatter epilogue (r3 lesson:
// LDS-repack epilogue write-amplified HBM 9x).
template<int OUT_BF16>
__global__ __launch_bounds__(512, 4) void sage_gemm(
    const u16* __restrict__ Aa, const u16* __restrict__ Ax,
    const u16* __restrict__ WT, const float* __restrict__ bias,
    void* __restrict__ out, int N) {
    __shared__ u16 Bl[128 * 256];       // 64 KB exactly
    int tid = threadIdx.x;

    // stage WT -> LDS, chunk (n,kc) stored at kc^(n&15)  [bank-spread swizzle]
    {
        const uint4* Wg = (const uint4*)WT;     // 4096 16B-chunks
        uint4* Bl4 = (uint4*)Bl;
        #pragma unroll
        for (int i = 0; i < 8; ++i) {
            int cid = tid + 512 * i;
            int n = cid >> 5;
            int kc = cid & 31;
            Bl4[(n << 5) | (kc ^ (n & 15))] = Wg[cid];
        }
    }
    __syncthreads();    // ALL waves reach this (no early return above)

    int wavein = tid >> 6;
    int lane = tid & 63;
    int col = lane & 15;
    int chunk = lane >> 4;
    int wid = blockIdx.x * 8 + wavein;

    // rows for the 2 m-tiles (clamped for tail-wave loads; stores guarded)
    size_t m0 = (size_t)wid * 32 + col;
    size_t m1 = m0 + 16;
    size_t m0c = (m0 < (size_t)N) ? m0 : (size_t)(N - 1);
    size_t m1c = (m1 < (size_t)N) ? m1 : (size_t)(N - 1);

    const bf16x8* a0p = (const bf16x8*)(Aa + m0c * 128 + chunk * 8);
    const bf16x8* a1p = (const bf16x8*)(Aa + m1c * 128 + chunk * 8);
    const bf16x8* x0p = (const bf16x8*)(Ax + m0c * 128 + chunk * 8);
    const bf16x8* x1p = (const bf16x8*)(Ax + m1c * 128 + chunk * 8);

    f32x4 acc0[8], acc1[8];
    #pragma unroll
    for (int t = 0; t < 8; ++t) {
        acc0[t] = (f32x4){0.f, 0.f, 0.f, 0.f};
        acc1[t] = (f32x4){0.f, 0.f, 0.f, 0.f};
    }

    // agg half: kc = 4s + chunk
    #pragma unroll
    for (int s = 0; s < 4; ++s) {
        bf16x8 a0 = a0p[s * 4];
        bf16x8 a1 = a1p[s * 4];
        int kc = s * 4 + chunk;
        #pragma unroll
        for (int t = 0; t < 8; ++t) {
            const bf16x8* bp = (const bf16x8*)(Bl + (((16 * t + col) << 8) | ((kc ^ col) << 3)));
            bf16x8 b = *bp;
            acc0[t] = __builtin_amdgcn_mfma_f32_16x16x32_bf16(a0, b, acc0[t], 0, 0, 0);
            acc1[t] = __builtin_amdgcn_mfma_f32_16x16x32_bf16(a1, b, acc1[t], 0, 0, 0);
        }
    }
    // x half: kc = 16 + 4s + chunk
    #pragma unroll
    for (int s = 0; s < 4; ++s) {
        bf16x8 a0 = x0p[s * 4];
        bf16x8 a1 = x1p[s * 4];
        int kc = 16 + s * 4 + chunk;
        #pragma unroll
        for (int t = 0; t < 8; ++t) {
            const bf16x8* bp = (const bf16x8*)(Bl + (((16 * t + col) << 8) | ((kc ^ col) << 3)));
            bf16x8 b = *bp;
            acc0[t] = __builtin_amdgcn_mfma_f32_16x16x32_bf16(a0, b, acc0[t], 0, 0, 0);
            acc1[t] = __builtin_amdgcn_mfma_f32_16x16x32_bf16(a1, b, acc1[t], 0, 0, 0);
        }
    }

    // epilogue: C/D layout col=lane&15, row=(lane>>4)*4+reg  [m89-verified]
    #pragma unroll
    for (int mt = 0; mt < 2; ++mt) {
        size_t row0 = (size_t)wid * 32 + mt * 16 + chunk * 4;
        #pragma unroll
        for (int t = 0; t < 8; ++t) {
            int n = 16 * t + col;
            float bv = bias[n];
            f32x4 a = mt ? acc1[t] : acc0[t];
            #pragma unroll
            for (int r = 0; r < 4; ++r) {
                size_t row = row0 + r;
                if (row < (size_t)N) {
                    float v = fmaxf(a[r] + bv, 0.f);
                    if (OUT_BF16) ((u16*)out)[row * 128 + n] = f_to_bf16(v);
                    else          ((float*)out)[row * 128 + n] = v;
                }
            }
        }
    }
}

extern "C" void kernel_launch(void* const* d_in, const int* in_sizes, int n_in,
                              void* d_out, int out_size, void* d_ws, size_t ws_size,
                              hipStream_t stream) {
    const float* x   = (const float*)d_in[0];
    const int*   ei  = (const int*)d_in[1];   // int64 -> int32 from harness
    const float* Wl1 = (const float*)d_in[2];
    const float* Wr1 = (const float*)d_in[3];
    const float* b1  = (const float*)d_in[4];
    const float* Wl2 = (const float*)d_in[5];
    const float* Wr2 = (const float*)d_in[6];
    const float* b2  = (const float*)d_in[7];
    float* out       = (float*)d_out;

    int N = in_sizes[0] / D;        // 100000
    int E = in_sizes[1] / 2;        // 1600000
    const int* src = ei;
    const int* dst = ei + E;
    int nbuck = (N + 1023) >> 10;   // 98

    // workspace carve-up (~40 MB)
    char* ws = (char*)d_ws;
    int* cnt       = (int*)ws;  ws += (size_t)N * 4;       // degrees
    int* seg_start = (int*)ws;  ws += (size_t)N * 4;       // segment bases
    int* bcur      = (int*)ws;  ws += 128 * CPAD * 4;      // padded bucket cursors
    int* gtotal    = (int*)ws;  ws += 4 * 4;               // global segment cursor
    ws = (char*)(((uintptr_t)ws + 255) & ~(uintptr_t)255);
    int* csr_src   = (int*)ws;  ws += (size_t)E * 4;
    ws = (char*)(((uintptr_t)ws + 255) & ~(uintptr_t)255);
    u16* WT1       = (u16*)ws;  ws += (size_t)128 * 256 * 2;
    u16* WT2       = (u16*)ws;  ws += (size_t)128 * 256 * 2;
    ws = (char*)(((uintptr_t)ws + 255) & ~(uintptr_t)255);
    u16* aggb      = (u16*)ws;  ws += (size_t)N * 128 * 2;
    ws = (char*)(((uintptr_t)ws + 255) & ~(uintptr_t)255);
    u16* h1b       = (u16*)ws;  ws += (size_t)N * 128 * 2;
    u16* xb        = (u16*)d_out;       // parks in d_out; dead before gemm2 writes out
    u32* pairs     = (u32*)aggb;        // 7.2 MB overlay; dead before aggregate writes aggb

    // zero padded bcur + gtotal (contiguous region) -- memset, no kernel launch
    hipMemsetAsync(bcur, 0, (size_t)(128 * CPAD + 4) * 4, stream);

    int binB  = (E + 4095) / 4096;      // 391
    int convB = 2048;                   // grid-stride float4 conversion
    int nf4   = N * (D / 4);            // 3.2M float4s
    prep_fused<<<binB + convB + 256, 256, 0, stream>>>(
        src, dst, E, nbuck, binB, pairs, bcur,
        x, xb, nf4, convB, Wl1, Wr1, Wl2, Wr2, WT1, WT2);

    build_csr<<<nbuck, 1024, 0, stream>>>(pairs, bcur, N, cnt, seg_start, gtotal, csr_src);

    int aggBlocks = (N + 3) / 4;
    int gemmBlocks = (N + 255) / 256;   // 8 waves/block x 32 rows/wave

    // layer 1
    aggregate_bf16<<<aggBlocks, 256, 0, stream>>>(xb, csr_src, seg_start, cnt, N, aggb);
    sage_gemm<1><<<gemmBlocks, 512, 0, stream>>>(aggb, xb, WT1, b1, h1b, N);

    // layer 2
    aggregate_bf16<<<aggBlocks, 256, 0, stream>>>(h1b, csr_src, seg_start, cnt, N, aggb);
    sage_gemm<0><<<gemmBlocks, 512, 0, stream>>>(aggb, h1b, WT2, b2, out, N);
}

// Round 10
// 302.825 us; speedup vs baseline: 1.3711x; 1.0093x over previous
//
#include <hip/hip_runtime.h>
#include <hip/hip_bf16.h>
#include <stdint.h>

#define D 128
#define SEGCAP 9216             // per-bucket pair/CSR capacity: mean 8192, +11 sigma
#define CPAD 32                 // bcur cursor padding: 1 cursor per 128B line
typedef unsigned short u16;
typedef unsigned int u32;
typedef __attribute__((ext_vector_type(8))) short bf16x8;
typedef __attribute__((ext_vector_type(4))) float f32x4;
typedef __attribute__((ext_vector_type(2))) float f32x2;
typedef __attribute__((ext_vector_type(2))) unsigned int u32x2;

// ---------- helpers ----------
__device__ inline u16 f_to_bf16(float f) {             // round-to-nearest-even
    u32 u = __builtin_bit_cast(u32, f);
    u += 0x7FFFu + ((u >> 16) & 1u);
    return (u16)(u >> 16);
}
__device__ inline u32 pack_bf16(float a, float b) {
    return (u32)f_to_bf16(a) | ((u32)f_to_bf16(b) << 16);
}

// ---------- fused prep: bin_edges (blocks [0,binB)) + convert_x + convert_w ----------
// 512-node buckets (196): halves LDS-atomic contention vs 1024-node buckets.
// pairs u32-packed (src<<9 | dst_local).
__global__ __launch_bounds__(256) void prep_fused(
    const int* __restrict__ src, const int* __restrict__ dst, int E, int nbuck, int binB,
    u32* __restrict__ pairs, int* __restrict__ bcur,
    const float* __restrict__ x, u16* __restrict__ xb, int nf4, int convB,
    const float* __restrict__ Wl1, const float* __restrict__ Wr1,
    const float* __restrict__ Wl2, const float* __restrict__ Wr2,
    u16* __restrict__ WT1, u16* __restrict__ WT2) {
    __shared__ int hist[256], gb[256], loc[256];
    int tid = threadIdx.x;
    int bid = blockIdx.x;
    if (bid < binB) {
        // ---- bin edges into 512-node buckets ----
        hist[tid] = 0; loc[tid] = 0;
        __syncthreads();
        int base = bid * 4096;
        int d[16], b[16];
        #pragma unroll
        for (int i = 0; i < 16; ++i) {
            int e = base + i * 256 + tid;
            d[i] = (e < E) ? dst[e] : -1;
            b[i] = (d[i] >= 0) ? (d[i] >> 9) : -1;
            if (b[i] >= 0) atomicAdd(&hist[b[i]], 1);
        }
        __syncthreads();
        if (tid < nbuck && hist[tid] > 0) gb[tid] = atomicAdd(&bcur[tid * CPAD], hist[tid]);
        __syncthreads();
        #pragma unroll
        for (int i = 0; i < 16; ++i) {
            if (b[i] >= 0) {
                int e = base + i * 256 + tid;
                int s = src[e];
                int r = atomicAdd(&loc[b[i]], 1);
                int pos = gb[b[i]] + r;
                if (pos < SEGCAP)   // overflow ~impossible for uniform-random edges
                    pairs[(size_t)b[i] * SEGCAP + pos] = ((u32)s << 9) | ((u32)d[i] & 511u);
            }
        }
    } else if (bid < binB + convB) {
        // ---- convert x fp32 -> bf16, float4-vectorized grid-stride ----
        int idx = (bid - binB) * 256 + tid;
        int stride = convB * 256;
        const float4* xf = (const float4*)x;
        uint2* xo = (uint2*)xb;
        for (int i = idx; i < nf4; i += stride) {
            float4 v = xf[i];
            xo[i] = make_uint2(pack_bf16(v.x, v.y), pack_bf16(v.z, v.w));
        }
    } else {
        // ---- convert weights -> WT[n][k] bf16, k = [Wl cols | Wr cols] ----
        int id = (bid - binB - convB) * 256 + tid;   // 256 blocks x 256 = 65536
        if (id < 2 * 128 * 256) {
            int which = id >> 15;
            int rem = id & 32767;
            int n = rem >> 8;
            int k = rem & 255;
            const float* Wl = which ? Wl2 : Wl1;
            const float* Wr = which ? Wr2 : Wr1;
            float v = (k < 128) ? Wl[k * 128 + n] : Wr[(k - 128) * 128 + n];
            u16* WT = which ? WT2 : WT1;
            WT[n * 256 + k] = f_to_bf16(v);
        }
    }
}

// ---------- phase 2: per-bucket CSR build, DETERMINISTIC bases ----------
// gbase = bk*SEGCAP (csr_src gapped; harmless -- aggregate uses seg_start/cnt).
// Deletes the gtotal atomic; whole 512-dst bucket stages in ONE LDS pass
// (was: count + 2 filtered half-passes). 196 blocks (vs 98), 512-wide scan.
__global__ __launch_bounds__(1024) void build_csr(
    const u32* __restrict__ pairs, const int* __restrict__ bcur, int N,
    int* __restrict__ cnt, int* __restrict__ seg_start,
    int* __restrict__ csr_src) {
    __shared__ int cnt_l[512];
    __shared__ int off_l[512];
    __shared__ int sblk[512];
    __shared__ u32 stage[SEGCAP];       // 36KB
    int tid = threadIdx.x;
    int bk = blockIdx.x;
    int n0 = bk << 9;
    int nN = min(512, N - n0);
    if (tid < 512) cnt_l[tid] = 0;
    __syncthreads();
    int m = min(bcur[bk * CPAD], SEGCAP);
    const u32* P = pairs + (size_t)bk * SEGCAP;
    for (int i = tid; i < m; i += 1024) {
        atomicAdd(&cnt_l[P[i] & 511u], 1);
    }
    __syncthreads();
    int c = (tid < 512) ? cnt_l[tid] : 0;
    if (tid < 512) sblk[tid] = c;
    for (int off = 1; off < 512; off <<= 1) {    // uniform loop: barrier-safe
        __syncthreads();
        int u = (tid < 512 && tid >= off) ? sblk[tid - off] : 0;
        __syncthreads();
        if (tid < 512) sblk[tid] += u;
    }
    __syncthreads();
    int gbase = bk * SEGCAP;
    if (tid < 512) {
        int excl = sblk[tid] - c;                // own slot only: no race
        off_l[tid] = excl;
        if (tid < nN) {
            cnt[n0 + tid] = c;
            seg_start[n0 + tid] = gbase + excl;
        }
        cnt_l[tid] = 0;                          // reuse as cursors
    }
    __syncthreads();
    int total = sblk[511];                       // <= m <= SEGCAP
    for (int i = tid; i < m; i += 1024) {
        u32 e = P[i];
        int dl = (int)(e & 511u);
        int r = atomicAdd(&cnt_l[dl], 1);
        stage[off_l[dl] + r] = e >> 9;           // bounded by m <= SEGCAP
    }
    __syncthreads();
    for (int j = tid; j < total; j += 1024)
        csr_src[gbase + j] = (int)stage[j];      // coalesced
}

// ---------- mean-aggregate: one wave/node, 16 lanes/row x 16B (round-2 form) ----------
// PINNED at its structural floor: random-256B gathers served by Infinity Cache
// at ~3.35TB/s (FETCH 179MB = L2-miss traffic, mostly L3-hit). Fusion attempts
// lost (r6 TLP collapse, r8 barrier straggler); slice-major re-layout is
// issue-bound by arithmetic (4x loads). Do not touch.
__global__ __launch_bounds__(256) void aggregate_bf16(
    const u16* __restrict__ xb, const int* __restrict__ csr_src,
    const int* __restrict__ seg_start, const int* __restrict__ cnt,
    int N, u16* __restrict__ agg) {
    int wave = threadIdx.x >> 6;
    int lane = threadIdx.x & 63;
    int n = blockIdx.x * (blockDim.x >> 6) + wave;
    if (n >= N) return;
    int s0 = seg_start[n];
    int deg = cnt[n];
    int sub = lane & 15;
    int eoff = lane >> 4;

    f32x2 acc2[4];
    #pragma unroll
    for (int i = 0; i < 4; ++i) acc2[i] = (f32x2){0.f, 0.f};

    for (int c0 = 0; c0 < deg; c0 += 64) {
        int chunkN = min(deg - c0, 64);
        int myidx = (lane < chunkN) ? csr_src[s0 + c0 + lane] : 0;  // coalesced
        for (int e0 = 0; e0 < chunkN; e0 += 16) {
            uint4 v[4];
            #pragma unroll
            for (int j = 0; j < 4; ++j) {
                int ej = e0 + j * 4 + eoff;
                if (e0 + j * 4 < chunkN) {          // wave-uniform: cheap skip
                    int s = __shfl(myidx, ej & 63);
                    if (ej < chunkN)                // per-lane: no dup loads
                        v[j] = ((const uint4*)(xb + (size_t)s * 128))[sub];
                }
            }
            #pragma unroll
            for (int j = 0; j < 4; ++j) {
                int ej = e0 + j * 4 + eoff;
                if (ej < chunkN) {
                    u32 w;
                    w = v[j].x; acc2[0] += __builtin_bit_cast(f32x2, (u32x2){w << 16, w & 0xFFFF0000u});
                    w = v[j].y; acc2[1] += __builtin_bit_cast(f32x2, (u32x2){w << 16, w & 0xFFFF0000u});
                    w = v[j].z; acc2[2] += __builtin_bit_cast(f32x2, (u32x2){w << 16, w & 0xFFFF0000u});
                    w = v[j].w; acc2[3] += __builtin_bit_cast(f32x2, (u32x2){w << 16, w & 0xFFFF0000u});
                }
            }
        }
    }

    float a[8];
    #pragma unroll
    for (int i = 0; i < 4; ++i) { a[2 * i] = acc2[i].x; a[2 * i + 1] = acc2[i].y; }
    #pragma unroll
    for (int i = 0; i < 8; ++i) {
        a[i] += __shfl_xor(a[i], 16);
        a[i] += __shfl_xor(a[i], 32);
    }

    if (eoff == 0) {
        float inv = 1.0f / fmaxf((float)deg, 1.0f);
        uint4 o;
        o.x = pack_bf16(a[0] * inv, a[1] * inv);
        o.y = pack_bf16(a[2] * inv, a[3] * inv);
        o.z = pack_bf16(a[4] * inv, a[5] * inv);
        o.w = pack_bf16(a[6] * inv, a[7] * inv);
        ((uint4*)(agg + (size_t)n * 128))[sub] = o;
    }
}

// ---------- fused GEMM: out = relu([Aa|Ax] @ WT^T + bias) via MFMA ----------
// 512-thread blocks: 8 waves share ONE 64KB B-stage -> 4 waves/SIMD (r9: -16us
// vs 256-thread form). B staged with 16B-chunk XOR swizzle; direct-scatter
// epilogue (r3: LDS-repack epilogue write-amplified HBM 9x).
template<int OUT_BF16>
__global__ __launch_bounds__(512, 4) void sage_gemm(
    const u16* __restrict__ Aa, const u16* __restrict__ Ax,
    const u16* __restrict__ WT, const float* __restrict__ bias,
    void* __restrict__ out, int N) {
    __shared__ u16 Bl[128 * 256];       // 64 KB exactly
    int tid = threadIdx.x;

    // stage WT -> LDS, chunk (n,kc) stored at kc^(n&15)  [bank-spread swizzle]
    {
        const uint4* Wg = (const uint4*)WT;     // 4096 16B-chunks
        uint4* Bl4 = (uint4*)Bl;
        #pragma unroll
        for (int i = 0; i < 8; ++i) {
            int cid = tid + 512 * i;
            int n = cid >> 5;
            int kc = cid & 31;
            Bl4[(n << 5) | (kc ^ (n & 15))] = Wg[cid];
        }
    }
    __syncthreads();    // ALL waves reach this (no early return above)

    int wavein = tid >> 6;
    int lane = tid & 63;
    int col = lane & 15;
    int chunk = lane >> 4;
    int wid = blockIdx.x * 8 + wavein;

    // rows for the 2 m-tiles (clamped for tail-wave loads; stores guarded)
    size_t m0 = (size_t)wid * 32 + col;
    size_t m1 = m0 + 16;
    size_t m0c = (m0 < (size_t)N) ? m0 : (size_t)(N - 1);
    size_t m1c = (m1 < (size_t)N) ? m1 : (size_t)(N - 1);

    const bf16x8* a0p = (const bf16x8*)(Aa + m0c * 128 + chunk * 8);
    const bf16x8* a1p = (const bf16x8*)(Aa + m1c * 128 + chunk * 8);
    const bf16x8* x0p = (const bf16x8*)(Ax + m0c * 128 + chunk * 8);
    const bf16x8* x1p = (const bf16x8*)(Ax + m1c * 128 + chunk * 8);

    f32x4 acc0[8], acc1[8];
    #pragma unroll
    for (int t = 0; t < 8; ++t) {
        acc0[t] = (f32x4){0.f, 0.f, 0.f, 0.f};
        acc1[t] = (f32x4){0.f, 0.f, 0.f, 0.f};
    }

    // agg half: kc = 4s + chunk
    #pragma unroll
    for (int s = 0; s < 4; ++s) {
        bf16x8 a0 = a0p[s * 4];
        bf16x8 a1 = a1p[s * 4];
        int kc = s * 4 + chunk;
        #pragma unroll
        for (int t = 0; t < 8; ++t) {
            const bf16x8* bp = (const bf16x8*)(Bl + (((16 * t + col) << 8) | ((kc ^ col) << 3)));
            bf16x8 b = *bp;
            acc0[t] = __builtin_amdgcn_mfma_f32_16x16x32_bf16(a0, b, acc0[t], 0, 0, 0);
            acc1[t] = __builtin_amdgcn_mfma_f32_16x16x32_bf16(a1, b, acc1[t], 0, 0, 0);
        }
    }
    // x half: kc = 16 + 4s + chunk
    #pragma unroll
    for (int s = 0; s < 4; ++s) {
        bf16x8 a0 = x0p[s * 4];
        bf16x8 a1 = x1p[s * 4];
        int kc = 16 + s * 4 + chunk;
        #pragma unroll
        for (int t = 0; t < 8; ++t) {
            const bf16x8* bp = (const bf16x8*)(Bl + (((16 * t + col) << 8) | ((kc ^ col) << 3)));
            bf16x8 b = *bp;
            acc0[t] = __builtin_amdgcn_mfma_f32_16x16x32_bf16(a0, b, acc0[t], 0, 0, 0);
            acc1[t] = __builtin_amdgcn_mfma_f32_16x16x32_bf16(a1, b, acc1[t], 0, 0, 0);
        }
    }

    // epilogue: C/D layout col=lane&15, row=(lane>>4)*4+reg  [m89-verified]
    #pragma unroll
    for (int mt = 0; mt < 2; ++mt) {
        size_t row0 = (size_t)wid * 32 + mt * 16 + chunk * 4;
        #pragma unroll
        for (int t = 0; t < 8; ++t) {
            int n = 16 * t + col;
            float bv = bias[n];
            f32x4 a = mt ? acc1[t] : acc0[t];
            #pragma unroll
            for (int r = 0; r < 4; ++r) {
                size_t row = row0 + r;
                if (row < (size_t)N) {
                    float v = fmaxf(a[r] + bv, 0.f);
                    if (OUT_BF16) ((u16*)out)[row * 128 + n] = f_to_bf16(v);
                    else          ((float*)out)[row * 128 + n] = v;
                }
            }
        }
    }
}

extern "C" void kernel_launch(void* const* d_in, const int* in_sizes, int n_in,
                              void* d_out, int out_size, void* d_ws, size_t ws_size,
                              hipStream_t stream) {
    const float* x   = (const float*)d_in[0];
    const int*   ei  = (const int*)d_in[1];   // int64 -> int32 from harness
    const float* Wl1 = (const float*)d_in[2];
    const float* Wr1 = (const float*)d_in[3];
    const float* b1  = (const float*)d_in[4];
    const float* Wl2 = (const float*)d_in[5];
    const float* Wr2 = (const float*)d_in[6];
    const float* b2  = (const float*)d_in[7];
    float* out       = (float*)d_out;

    int N = in_sizes[0] / D;        // 100000
    int E = in_sizes[1] / 2;        // 1600000
    const int* src = ei;
    const int* dst = ei + E;
    int nbuck = (N + 511) >> 9;     // 196 buckets of 512 nodes

    // workspace carve-up
    char* ws = (char*)d_ws;
    int* cnt       = (int*)ws;  ws += (size_t)N * 4;       // degrees
    int* seg_start = (int*)ws;  ws += (size_t)N * 4;       // segment bases
    int* bcur      = (int*)ws;  ws += 256 * CPAD * 4;      // padded bucket cursors
    ws = (char*)(((uintptr_t)ws + 255) & ~(uintptr_t)255);
    int* csr_src   = (int*)ws;  ws += (size_t)256 * SEGCAP * 4;   // gapped CSR, 9.4 MB
    ws = (char*)(((uintptr_t)ws + 255) & ~(uintptr_t)255);
    u16* WT1       = (u16*)ws;  ws += (size_t)128 * 256 * 2;
    u16* WT2       = (u16*)ws;  ws += (size_t)128 * 256 * 2;
    ws = (char*)(((uintptr_t)ws + 255) & ~(uintptr_t)255);
    u16* aggb      = (u16*)ws;  ws += (size_t)N * 128 * 2;
    ws = (char*)(((uintptr_t)ws + 255) & ~(uintptr_t)255);
    u16* h1b       = (u16*)ws;  ws += (size_t)N * 128 * 2;
    u16* xb        = (u16*)d_out;       // parks in d_out; dead before gemm2 writes out
    u32* pairs     = (u32*)aggb;        // 7.2 MB overlay; dead before aggregate writes aggb

    // zero padded bcur -- memset, no kernel launch
    hipMemsetAsync(bcur, 0, (size_t)(256 * CPAD) * 4, stream);

    int binB  = (E + 4095) / 4096;      // 391
    int convB = 2048;                   // grid-stride float4 conversion
    int nf4   = N * (D / 4);            // 3.2M float4s
    prep_fused<<<binB + convB + 256, 256, 0, stream>>>(
        src, dst, E, nbuck, binB, pairs, bcur,
        x, xb, nf4, convB, Wl1, Wr1, Wl2, Wr2, WT1, WT2);

    build_csr<<<nbuck, 1024, 0, stream>>>(pairs, bcur, N, cnt, seg_start, csr_src);

    int aggBlocks = (N + 3) / 4;
    int gemmBlocks = (N + 255) / 256;   // 8 waves/block x 32 rows/wave

    // layer 1
    aggregate_bf16<<<aggBlocks, 256, 0, stream>>>(xb, csr_src, seg_start, cnt, N, aggb);
    sage_gemm<1><<<gemmBlocks, 512, 0, stream>>>(aggb, xb, WT1, b1, h1b, N);

    // layer 2
    aggregate_bf16<<<aggBlocks, 256, 0, stream>>>(h1b, csr_src, seg_start, cnt, N, aggb);
    sage_gemm<0><<<gemmBlocks, 512, 0, stream>>>(aggb, h1b, WT2, b2, out, N);
}

// Round 11
// 291.952 us; speedup vs baseline: 1.4222x; 1.0372x over previous
//
#include <hip/hip_runtime.h>
#include <hip/hip_bf16.h>
#include <stdint.h>

#define D 128
#define SEGCAP 9216             // per-bucket pair/CSR capacity: mean 8192, +11 sigma
#define CPAD 32                 // bcur cursor padding: 1 cursor per 128B line
typedef unsigned short u16;
typedef unsigned int u32;
typedef __attribute__((ext_vector_type(8))) short bf16x8;
typedef __attribute__((ext_vector_type(4))) float f32x4;
typedef __attribute__((ext_vector_type(2))) float f32x2;
typedef __attribute__((ext_vector_type(2))) unsigned int u32x2;

// ---------- helpers ----------
__device__ inline u16 f_to_bf16(float f) {             // round-to-nearest-even
    u32 u = __builtin_bit_cast(u32, f);
    u += 0x7FFFu + ((u >> 16) & 1u);
    return (u16)(u >> 16);
}
__device__ inline u32 pack_bf16(float a, float b) {
    return (u32)f_to_bf16(a) | ((u32)f_to_bf16(b) << 16);
}

// ---------- fused prep: bin_edges (blocks [0,binB)) + convert_x + convert_w ----------
// Bin phase now counting-sorts the block's 4096 edges in LDS and writes
// pairs as bucket-contiguous runs (~84B), replacing fully-scattered 4B
// stores (64 distinct 64B lines per wave-store, ~16x write amplification).
__global__ __launch_bounds__(256) void prep_fused(
    const int* __restrict__ src, const int* __restrict__ dst, int E, int nbuck, int binB,
    u32* __restrict__ pairs, int* __restrict__ bcur,
    const float* __restrict__ x, u16* __restrict__ xb, int nf4, int convB,
    const float* __restrict__ Wl1, const float* __restrict__ Wr1,
    const float* __restrict__ Wl2, const float* __restrict__ Wr2,
    u16* __restrict__ WT1, u16* __restrict__ WT2) {
    __shared__ int hist[256], off[256], gb[256], loc[256];
    __shared__ u32 stageE[4096];            // 16KB: edges grouped by bucket
    __shared__ unsigned char stageB[4096];  // 4KB: bucket id per staged edge
    int tid = threadIdx.x;
    int bid = blockIdx.x;
    if (bid < binB) {
        // ---- bin edges into 512-node buckets, LDS counting-sort ----
        hist[tid] = 0; loc[tid] = 0;
        __syncthreads();
        int base = bid * 4096;
        int d[16], s[16], b[16];
        #pragma unroll
        for (int i = 0; i < 16; ++i) {
            int e = base + i * 256 + tid;
            d[i] = (e < E) ? dst[e] : -1;
            s[i] = (e < E) ? src[e] : 0;
            b[i] = (d[i] >= 0) ? (d[i] >> 9) : -1;
            if (b[i] >= 0) atomicAdd(&hist[b[i]], 1);
        }
        __syncthreads();
        int c = hist[tid];
        off[tid] = c;
        for (int o = 1; o < 256; o <<= 1) {     // uniform loop: barrier-safe
            __syncthreads();
            int u = (tid >= o) ? off[tid - o] : 0;
            __syncthreads();
            off[tid] += u;
        }
        __syncthreads();
        int total = off[255];
        int excl = off[tid] - c;
        if (tid < nbuck && c > 0) gb[tid] = atomicAdd(&bcur[tid * CPAD], c);
        __syncthreads();
        off[tid] = excl;                        // overwrite inclusive -> exclusive
        __syncthreads();
        #pragma unroll
        for (int i = 0; i < 16; ++i) {
            if (b[i] >= 0) {
                int r = atomicAdd(&loc[b[i]], 1);
                int j = off[b[i]] + r;
                stageE[j] = ((u32)s[i] << 9) | ((u32)d[i] & 511u);
                stageB[j] = (unsigned char)b[i];
            }
        }
        __syncthreads();
        for (int j = tid; j < total; j += 256) {    // bucket-run coalesced writes
            int bb = stageB[j];
            int pos = gb[bb] + (j - off[bb]);
            if (pos < SEGCAP)   // overflow ~impossible for uniform-random edges
                pairs[(size_t)bb * SEGCAP + pos] = stageE[j];
        }
    } else if (bid < binB + convB) {
        // ---- convert x fp32 -> bf16, float4-vectorized grid-stride ----
        int idx = (bid - binB) * 256 + tid;
        int stride = convB * 256;
        const float4* xf = (const float4*)x;
        uint2* xo = (uint2*)xb;
        for (int i = idx; i < nf4; i += stride) {
            float4 v = xf[i];
            xo[i] = make_uint2(pack_bf16(v.x, v.y), pack_bf16(v.z, v.w));
        }
    } else {
        // ---- convert weights -> WT[n][k] bf16, k = [Wl cols | Wr cols] ----
        int id = (bid - binB - convB) * 256 + tid;   // 256 blocks x 256 = 65536
        if (id < 2 * 128 * 256) {
            int which = id >> 15;
            int rem = id & 32767;
            int n = rem >> 8;
            int k = rem & 255;
            const float* Wl = which ? Wl2 : Wl1;
            const float* Wr = which ? Wr2 : Wr1;
            float v = (k < 128) ? Wl[k * 128 + n] : Wr[(k - 128) * 128 + n];
            u16* WT = which ? WT2 : WT1;
            WT[n * 256 + k] = f_to_bf16(v);
        }
    }
}

// ---------- phase 2: per-bucket CSR build, DETERMINISTIC bases ----------
// gbase = bk*SEGCAP (csr_src gapped; harmless -- aggregate uses seg_start/cnt).
__global__ __launch_bounds__(1024) void build_csr(
    const u32* __restrict__ pairs, const int* __restrict__ bcur, int N,
    int* __restrict__ cnt, int* __restrict__ seg_start,
    int* __restrict__ csr_src) {
    __shared__ int cnt_l[512];
    __shared__ int off_l[512];
    __shared__ int sblk[512];
    __shared__ u32 stage[SEGCAP];       // 36KB
    int tid = threadIdx.x;
    int bk = blockIdx.x;
    int n0 = bk << 9;
    int nN = min(512, N - n0);
    if (tid < 512) cnt_l[tid] = 0;
    __syncthreads();
    int m = min(bcur[bk * CPAD], SEGCAP);
    const u32* P = pairs + (size_t)bk * SEGCAP;
    for (int i = tid; i < m; i += 1024) {
        atomicAdd(&cnt_l[P[i] & 511u], 1);
    }
    __syncthreads();
    int c = (tid < 512) ? cnt_l[tid] : 0;
    if (tid < 512) sblk[tid] = c;
    for (int off = 1; off < 512; off <<= 1) {    // uniform loop: barrier-safe
        __syncthreads();
        int u = (tid < 512 && tid >= off) ? sblk[tid - off] : 0;
        __syncthreads();
        if (tid < 512) sblk[tid] += u;
    }
    __syncthreads();
    int gbase = bk * SEGCAP;
    if (tid < 512) {
        int excl = sblk[tid] - c;                // own slot only: no race
        off_l[tid] = excl;
        if (tid < nN) {
            cnt[n0 + tid] = c;
            seg_start[n0 + tid] = gbase + excl;
        }
        cnt_l[tid] = 0;                          // reuse as cursors
    }
    __syncthreads();
    int total = sblk[511];                       // <= m <= SEGCAP
    for (int i = tid; i < m; i += 1024) {
        u32 e = P[i];
        int dl = (int)(e & 511u);
        int r = atomicAdd(&cnt_l[dl], 1);
        stage[off_l[dl] + r] = e >> 9;           // bounded by m <= SEGCAP
    }
    __syncthreads();
    for (int j = tid; j < total; j += 1024)
        csr_src[gbase + j] = (int)stage[j];      // coalesced
}

// ---------- mean-aggregate: one wave/node, 16 lanes/row x 16B (round-2 form) ----------
// PINNED at its structural floor: random-256B gathers served by Infinity Cache
// at ~3.3TB/s (FETCH 179MB = L2-miss traffic, mostly L3-hit). Fusion attempts
// lost (r6 TLP collapse, r8 barrier straggler); slice-major re-layout is
// issue-bound by arithmetic (4x loads). Do not touch.
__global__ __launch_bounds__(256) void aggregate_bf16(
    const u16* __restrict__ xb, const int* __restrict__ csr_src,
    const int* __restrict__ seg_start, const int* __restrict__ cnt,
    int N, u16* __restrict__ agg) {
    int wave = threadIdx.x >> 6;
    int lane = threadIdx.x & 63;
    int n = blockIdx.x * (blockDim.x >> 6) + wave;
    if (n >= N) return;
    int s0 = seg_start[n];
    int deg = cnt[n];
    int sub = lane & 15;
    int eoff = lane >> 4;

    f32x2 acc2[4];
    #pragma unroll
    for (int i = 0; i < 4; ++i) acc2[i] = (f32x2){0.f, 0.f};

    for (int c0 = 0; c0 < deg; c0 += 64) {
        int chunkN = min(deg - c0, 64);
        int myidx = (lane < chunkN) ? csr_src[s0 + c0 + lane] : 0;  // coalesced
        for (int e0 = 0; e0 < chunkN; e0 += 16) {
            uint4 v[4];
            #pragma unroll
            for (int j = 0; j < 4; ++j) {
                int ej = e0 + j * 4 + eoff;
                if (e0 + j * 4 < chunkN) {          // wave-uniform: cheap skip
                    int s = __shfl(myidx, ej & 63);
                    if (ej < chunkN)                // per-lane: no dup loads
                        v[j] = ((const uint4*)(xb + (size_t)s * 128))[sub];
                }
            }
            #pragma unroll
            for (int j = 0; j < 4; ++j) {
                int ej = e0 + j * 4 + eoff;
                if (ej < chunkN) {
                    u32 w;
                    w = v[j].x; acc2[0] += __builtin_bit_cast(f32x2, (u32x2){w << 16, w & 0xFFFF0000u});
                    w = v[j].y; acc2[1] += __builtin_bit_cast(f32x2, (u32x2){w << 16, w & 0xFFFF0000u});
                    w = v[j].z; acc2[2] += __builtin_bit_cast(f32x2, (u32x2){w << 16, w & 0xFFFF0000u});
                    w = v[j].w; acc2[3] += __builtin_bit_cast(f32x2, (u32x2){w << 16, w & 0xFFFF0000u});
                }
            }
        }
    }

    float a[8];
    #pragma unroll
    for (int i = 0; i < 4; ++i) { a[2 * i] = acc2[i].x; a[2 * i + 1] = acc2[i].y; }
    #pragma unroll
    for (int i = 0; i < 8; ++i) {
        a[i] += __shfl_xor(a[i], 16);
        a[i] += __shfl_xor(a[i], 32);
    }

    if (eoff == 0) {
        float inv = 1.0f / fmaxf((float)deg, 1.0f);
        uint4 o;
        o.x = pack_bf16(a[0] * inv, a[1] * inv);
        o.y = pack_bf16(a[2] * inv, a[3] * inv);
        o.z = pack_bf16(a[4] * inv, a[5] * inv);
        o.w = pack_bf16(a[6] * inv, a[7] * inv);
        ((uint4*)(agg + (size_t)n * 128))[sub] = o;
    }
}

// ---------- fused GEMM: out = relu([Aa|Ax] @ WT^T + bias) via MFMA ----------
// 512-thread blocks: 8 waves share ONE 64KB B-stage -> 4 waves/SIMD (r9: -16us
// vs 256-thread form). B staged with 16B-chunk XOR swizzle; direct-scatter
// epilogue (r3: LDS-repack epilogue write-amplified HBM 9x).
template<int OUT_BF16>
__global__ __launch_bounds__(512, 4) void sage_gemm(
    const u16* __restrict__ Aa, const u16* __restrict__ Ax,
    const u16* __restrict__ WT, const float* __restrict__ bias,
    void* __restrict__ out, int N) {
    __shared__ u16 Bl[128 * 256];       // 64 KB exactly
    int tid = threadIdx.x;

    // stage WT -> LDS, chunk (n,kc) stored at kc^(n&15)  [bank-spread swizzle]
    {
        const uint4* Wg = (const uint4*)WT;     // 4096 16B-chunks
        uint4* Bl4 = (uint4*)Bl;
        #pragma unroll
        for (int i = 0; i < 8; ++i) {
            int cid = tid + 512 * i;
            int n = cid >> 5;
            int kc = cid & 31;
            Bl4[(n << 5) | (kc ^ (n & 15))] = Wg[cid];
        }
    }
    __syncthreads();    // ALL waves reach this (no early return above)

    int wavein = tid >> 6;
    int lane = tid & 63;
    int col = lane & 15;
    int chunk = lane >> 4;
    int wid = blockIdx.x * 8 + wavein;

    // rows for the 2 m-tiles (clamped for tail-wave loads; stores guarded)
    size_t m0 = (size_t)wid * 32 + col;
    size_t m1 = m0 + 16;
    size_t m0c = (m0 < (size_t)N) ? m0 : (size_t)(N - 1);
    size_t m1c = (m1 < (size_t)N) ? m1 : (size_t)(N - 1);

    const bf16x8* a0p = (const bf16x8*)(Aa + m0c * 128 + chunk * 8);
    const bf16x8* a1p = (const bf16x8*)(Aa + m1c * 128 + chunk * 8);
    const bf16x8* x0p = (const bf16x8*)(Ax + m0c * 128 + chunk * 8);
    const bf16x8* x1p = (const bf16x8*)(Ax + m1c * 128 + chunk * 8);

    f32x4 acc0[8], acc1[8];
    #pragma unroll
    for (int t = 0; t < 8; ++t) {
        acc0[t] = (f32x4){0.f, 0.f, 0.f, 0.f};
        acc1[t] = (f32x4){0.f, 0.f, 0.f, 0.f};
    }

    // agg half: kc = 4s + chunk
    #pragma unroll
    for (int s = 0; s < 4; ++s) {
        bf16x8 a0 = a0p[s * 4];
        bf16x8 a1 = a1p[s * 4];
        int kc = s * 4 + chunk;
        #pragma unroll
        for (int t = 0; t < 8; ++t) {
            const bf16x8* bp = (const bf16x8*)(Bl + (((16 * t + col) << 8) | ((kc ^ col) << 3)));
            bf16x8 b = *bp;
            acc0[t] = __builtin_amdgcn_mfma_f32_16x16x32_bf16(a0, b, acc0[t], 0, 0, 0);
            acc1[t] = __builtin_amdgcn_mfma_f32_16x16x32_bf16(a1, b, acc1[t], 0, 0, 0);
        }
    }
    // x half: kc = 16 + 4s + chunk
    #pragma unroll
    for (int s = 0; s < 4; ++s) {
        bf16x8 a0 = x0p[s * 4];
        bf16x8 a1 = x1p[s * 4];
        int kc = 16 + s * 4 + chunk;
        #pragma unroll
        for (int t = 0; t < 8; ++t) {
            const bf16x8* bp = (const bf16x8*)(Bl + (((16 * t + col) << 8) | ((kc ^ col) << 3)));
            bf16x8 b = *bp;
            acc0[t] = __builtin_amdgcn_mfma_f32_16x16x32_bf16(a0, b, acc0[t], 0, 0, 0);
            acc1[t] = __builtin_amdgcn_mfma_f32_16x16x32_bf16(a1, b, acc1[t], 0, 0, 0);
        }
    }

    // epilogue: C/D layout col=lane&15, row=(lane>>4)*4+reg  [m89-verified]
    #pragma unroll
    for (int mt = 0; mt < 2; ++mt) {
        size_t row0 = (size_t)wid * 32 + mt * 16 + chunk * 4;
        #pragma unroll
        for (int t = 0; t < 8; ++t) {
            int n = 16 * t + col;
            float bv = bias[n];
            f32x4 a = mt ? acc1[t] : acc0[t];
            #pragma unroll
            for (int r = 0; r < 4; ++r) {
                size_t row = row0 + r;
                if (row < (size_t)N) {
                    float v = fmaxf(a[r] + bv, 0.f);
                    if (OUT_BF16) ((u16*)out)[row * 128 + n] = f_to_bf16(v);
                    else          ((float*)out)[row * 128 + n] = v;
                }
            }
        }
    }
}

extern "C" void kernel_launch(void* const* d_in, const int* in_sizes, int n_in,
                              void* d_out, int out_size, void* d_ws, size_t ws_size,
                              hipStream_t stream) {
    const float* x   = (const float*)d_in[0];
    const int*   ei  = (const int*)d_in[1];   // int64 -> int32 from harness
    const float* Wl1 = (const float*)d_in[2];
    const float* Wr1 = (const float*)d_in[3];
    const float* b1  = (const float*)d_in[4];
    const float* Wl2 = (const float*)d_in[5];
    const float* Wr2 = (const float*)d_in[6];
    const float* b2  = (const float*)d_in[7];
    float* out       = (float*)d_out;

    int N = in_sizes[0] / D;        // 100000
    int E = in_sizes[1] / 2;        // 1600000
    const int* src = ei;
    const int* dst = ei + E;
    int nbuck = (N + 511) >> 9;     // 196 buckets of 512 nodes

    // workspace carve-up
    char* ws = (char*)d_ws;
    int* cnt       = (int*)ws;  ws += (size_t)N * 4;       // degrees
    int* seg_start = (int*)ws;  ws += (size_t)N * 4;       // segment bases
    int* bcur      = (int*)ws;  ws += 256 * CPAD * 4;      // padded bucket cursors
    ws = (char*)(((uintptr_t)ws + 255) & ~(uintptr_t)255);
    int* csr_src   = (int*)ws;  ws += (size_t)256 * SEGCAP * 4;   // gapped CSR, 9.4 MB
    ws = (char*)(((uintptr_t)ws + 255) & ~(uintptr_t)255);
    u16* WT1       = (u16*)ws;  ws += (size_t)128 * 256 * 2;
    u16* WT2       = (u16*)ws;  ws += (size_t)128 * 256 * 2;
    ws = (char*)(((uintptr_t)ws + 255) & ~(uintptr_t)255);
    u16* aggb      = (u16*)ws;  ws += (size_t)N * 128 * 2;
    ws = (char*)(((uintptr_t)ws + 255) & ~(uintptr_t)255);
    u16* h1b       = (u16*)ws;  ws += (size_t)N * 128 * 2;
    u16* xb        = (u16*)d_out;       // parks in d_out; dead before gemm2 writes out
    u32* pairs     = (u32*)aggb;        // 7.2 MB overlay; dead before aggregate writes aggb

    // zero padded bcur -- memset, no kernel launch
    hipMemsetAsync(bcur, 0, (size_t)(256 * CPAD) * 4, stream);

    int binB  = (E + 4095) / 4096;      // 391
    int convB = 2048;                   // grid-stride float4 conversion
    int nf4   = N * (D / 4);            // 3.2M float4s
    prep_fused<<<binB + convB + 256, 256, 0, stream>>>(
        src, dst, E, nbuck, binB, pairs, bcur,
        x, xb, nf4, convB, Wl1, Wr1, Wl2, Wr2, WT1, WT2);

    build_csr<<<nbuck, 1024, 0, stream>>>(pairs, bcur, N, cnt, seg_start, csr_src);

    int aggBlocks = (N + 3) / 4;
    int gemmBlocks = (N + 255) / 256;   // 8 waves/block x 32 rows/wave

    // layer 1
    aggregate_bf16<<<aggBlocks, 256, 0, stream>>>(xb, csr_src, seg_start, cnt, N, aggb);
    sage_gemm<1><<<gemmBlocks, 512, 0, stream>>>(aggb, xb, WT1, b1, h1b, N);

    // layer 2
    aggregate_bf16<<<aggBlocks, 256, 0, stream>>>(h1b, csr_src, seg_start, cnt, N, aggb);
    sage_gemm<0><<<gemmBlocks, 512, 0, stream>>>(aggb, h1b, WT2, b2, out, N);
}